// Round 1
// baseline (191.373 us; speedup 1.0000x reference)
//
#include <hip/hip_runtime.h>
#include <math.h>

// CPMLoss forward on MI355X.
// Fixed problem geometry: inputs [4*P*K, D] = [8192, 4096] f32, P=128, K=16.
// Pipeline:
//   1) centers_kernel : c[m][p][d] = mean_k inputs[m,p,k,d]           (HBM-bound, 128 MiB read)
//   2) offmin_kernel  : anNN[m][i] = min_{j!=i} ||c[m][i]-c[m][j]||   (L2-bound)
//   3) diag_kernel    : ap123/an123/ap124/an124 per identity
//   4) loss_kernel    : weighted relu-mean -> scalar
#define P_IDS 128
#define MARGIN_F 0.2f

__global__ __launch_bounds__(256) void centers_kernel(const float* __restrict__ in,
                                                      float* __restrict__ c,
                                                      int K, int D) {
    const int b = blockIdx.x;                      // m*P + p   (512 blocks)
    const float* src = in + (size_t)b * K * D;
    float* dst = c + (size_t)b * D;
    const float inv = 1.0f / (float)K;
    const int D4 = D >> 2;
    for (int d4 = threadIdx.x; d4 < D4; d4 += blockDim.x) {
        float4 acc = make_float4(0.f, 0.f, 0.f, 0.f);
        for (int k = 0; k < K; ++k) {
            float4 v = reinterpret_cast<const float4*>(src + (size_t)k * D)[d4];
            acc.x += v.x; acc.y += v.y; acc.z += v.z; acc.w += v.w;
        }
        acc.x *= inv; acc.y *= inv; acc.z *= inv; acc.w *= inv;
        reinterpret_cast<float4*>(dst)[d4] = acc;
    }
}

// One block per (modality m, identity i). Row i staged in LDS; each of the 4
// waves owns j = wave, wave+4, ... and shuffle-reduces the squared distance.
__global__ __launch_bounds__(256) void offmin_kernel(const float* __restrict__ c,
                                                     float* __restrict__ anmin,
                                                     int D) {
    __shared__ float lds[4096];     // D == 4096 floats, 16 KiB
    __shared__ float wmin[4];
    const int b = blockIdx.x;       // m*P + i
    const int m = b >> 7;
    const int i = b & (P_IDS - 1);
    const float* base = c + (size_t)m * P_IDS * D;
    const float* rowi = base + (size_t)i * D;
    const int D4 = D >> 2;
    for (int d4 = threadIdx.x; d4 < D4; d4 += blockDim.x)
        reinterpret_cast<float4*>(lds)[d4] =
            reinterpret_cast<const float4*>(rowi)[d4];
    __syncthreads();
    const int wave = threadIdx.x >> 6;
    const int lane = threadIdx.x & 63;
    float mn = INFINITY;
    for (int j = wave; j < P_IDS; j += 4) {
        if (j == i) continue;
        const float4* rowj = reinterpret_cast<const float4*>(base + (size_t)j * D);
        const float4* li = reinterpret_cast<const float4*>(lds);
        float acc = 0.f;
        for (int t = lane; t < D4; t += 64) {
            float4 a = li[t];
            float4 v = rowj[t];
            float dx = a.x - v.x, dy = a.y - v.y, dz = a.z - v.z, dw = a.w - v.w;
            acc = fmaf(dx, dx, acc); acc = fmaf(dy, dy, acc);
            acc = fmaf(dz, dz, acc); acc = fmaf(dw, dw, acc);
        }
        #pragma unroll
        for (int off = 32; off > 0; off >>= 1) acc += __shfl_down(acc, off, 64);
        if (lane == 0) {
            float d = sqrtf(fmaxf(acc, 1e-12f));
            mn = fminf(mn, d);
        }
    }
    if (lane == 0) wmin[wave] = mn;
    __syncthreads();
    if (threadIdx.x == 0)
        anmin[b] = fminf(fminf(wmin[0], wmin[1]), fminf(wmin[2], wmin[3]));
}

// One block per identity i: the four cross-modality diagonal distances.
__global__ __launch_bounds__(256) void diag_kernel(const float* __restrict__ c,
                                                   float* __restrict__ diag,
                                                   int D) {
    const int i = blockIdx.x;
    const size_t PD = (size_t)P_IDS * D;
    const float4* r1 = reinterpret_cast<const float4*>(c + 0 * PD + (size_t)i * D);
    const float4* r2 = reinterpret_cast<const float4*>(c + 1 * PD + (size_t)i * D);
    const float4* r3 = reinterpret_cast<const float4*>(c + 2 * PD + (size_t)i * D);
    const float4* r4 = reinterpret_cast<const float4*>(c + 3 * PD + (size_t)i * D);
    const int D4 = D >> 2;
    float a23 = 0.f, a13 = 0.f, a14 = 0.f, a24 = 0.f;
    for (int t = threadIdx.x; t < D4; t += blockDim.x) {
        float4 v1 = r1[t], v2 = r2[t], v3 = r3[t], v4 = r4[t];
        float dx, dy, dz, dw;
        dx = v2.x - v3.x; dy = v2.y - v3.y; dz = v2.z - v3.z; dw = v2.w - v3.w;
        a23 = fmaf(dx, dx, a23); a23 = fmaf(dy, dy, a23);
        a23 = fmaf(dz, dz, a23); a23 = fmaf(dw, dw, a23);
        dx = v1.x - v3.x; dy = v1.y - v3.y; dz = v1.z - v3.z; dw = v1.w - v3.w;
        a13 = fmaf(dx, dx, a13); a13 = fmaf(dy, dy, a13);
        a13 = fmaf(dz, dz, a13); a13 = fmaf(dw, dw, a13);
        dx = v1.x - v4.x; dy = v1.y - v4.y; dz = v1.z - v4.z; dw = v1.w - v4.w;
        a14 = fmaf(dx, dx, a14); a14 = fmaf(dy, dy, a14);
        a14 = fmaf(dz, dz, a14); a14 = fmaf(dw, dw, a14);
        dx = v2.x - v4.x; dy = v2.y - v4.y; dz = v2.z - v4.z; dw = v2.w - v4.w;
        a24 = fmaf(dx, dx, a24); a24 = fmaf(dy, dy, a24);
        a24 = fmaf(dz, dz, a24); a24 = fmaf(dw, dw, a24);
    }
    const int wave = threadIdx.x >> 6, lane = threadIdx.x & 63;
    #pragma unroll
    for (int off = 32; off > 0; off >>= 1) {
        a23 += __shfl_down(a23, off, 64);
        a13 += __shfl_down(a13, off, 64);
        a14 += __shfl_down(a14, off, 64);
        a24 += __shfl_down(a24, off, 64);
    }
    __shared__ float red[4][4];
    if (lane == 0) {
        red[wave][0] = a23; red[wave][1] = a13;
        red[wave][2] = a14; red[wave][3] = a24;
    }
    __syncthreads();
    if (threadIdx.x == 0) {
        float s23 = red[0][0] + red[1][0] + red[2][0] + red[3][0];
        float s13 = red[0][1] + red[1][1] + red[2][1] + red[3][1];
        float s14 = red[0][2] + red[1][2] + red[2][2] + red[3][2];
        float s24 = red[0][3] + red[1][3] + red[2][3] + red[3][3];
        diag[0 * P_IDS + i] = sqrtf(fmaxf(s23, 1e-12f));  // ap123 = ||c2-c3||
        diag[1 * P_IDS + i] = sqrtf(fmaxf(s13, 1e-12f));  // an123 = ||c1-c3||
        diag[2 * P_IDS + i] = sqrtf(fmaxf(s14, 1e-12f));  // ap124 = ||c1-c4||
        diag[3 * P_IDS + i] = sqrtf(fmaxf(s24, 1e-12f));  // an124 = ||c2-c4||
    }
}

__global__ __launch_bounds__(128) void loss_kernel(const float* __restrict__ anmin,
                                                   const float* __restrict__ diag,
                                                   float* __restrict__ out) {
    const int i = threadIdx.x;  // 0..127 == identity
    float ap123 = diag[0 * P_IDS + i], an123 = diag[1 * P_IDS + i];
    float ap124 = diag[2 * P_IDS + i], an124 = diag[3 * P_IDS + i];
    float an11 = anmin[0 * P_IDS + i], an22 = anmin[1 * P_IDS + i];
    float an33 = anmin[2 * P_IDS + i], an44 = anmin[3 * P_IDS + i];
    float s = fmaxf(ap123 - an123 + MARGIN_F, 0.f)
            + 0.5f * (fmaxf(ap123 - an33 + MARGIN_F, 0.f) +
                      fmaxf(ap123 - an11 + MARGIN_F, 0.f))
            + fmaxf(ap124 - an124 + MARGIN_F, 0.f)
            + 0.5f * (fmaxf(ap124 - an44 + MARGIN_F, 0.f) +
                      fmaxf(ap124 - an22 + MARGIN_F, 0.f));
    #pragma unroll
    for (int off = 32; off > 0; off >>= 1) s += __shfl_down(s, off, 64);
    __shared__ float w[2];
    if ((threadIdx.x & 63) == 0) w[threadIdx.x >> 6] = s;
    __syncthreads();
    if (threadIdx.x == 0) out[0] = (w[0] + w[1]) / (2.0f * (float)P_IDS);
}

extern "C" void kernel_launch(void* const* d_in, const int* in_sizes, int n_in,
                              void* d_out, int out_size, void* d_ws, size_t ws_size,
                              hipStream_t stream) {
    const float* in = (const float*)d_in[0];
    const int N = in_sizes[1];            // 8192 total rows (targets count)
    const int D = in_sizes[0] / N;        // 4096
    const int K = N / (4 * P_IDS);        // 16

    float* c     = (float*)d_ws;                       // 4*P*D f32 = 8 MiB
    float* anmin = c + (size_t)4 * P_IDS * D;          // 4*P f32
    float* diag  = anmin + 4 * P_IDS;                  // 4*P f32

    hipLaunchKernelGGL(centers_kernel, dim3(4 * P_IDS), dim3(256), 0, stream,
                       in, c, K, D);
    hipLaunchKernelGGL(offmin_kernel, dim3(4 * P_IDS), dim3(256), 0, stream,
                       c, anmin, D);
    hipLaunchKernelGGL(diag_kernel, dim3(P_IDS), dim3(256), 0, stream,
                       c, diag, D);
    hipLaunchKernelGGL(loss_kernel, dim3(1), dim3(128), 0, stream,
                       anmin, diag, (float*)d_out);
}

// Round 2
// 52.497 us; speedup vs baseline: 3.6454x; 3.6454x over previous
//
#include <hip/hip_runtime.h>
#include <math.h>

// CPMLoss forward on MI355X. Fixed geometry: inputs [8192,4096] f32, P=128, K=16, 4 modalities.
// Pipeline:
//   1) centers_kernel      : c[m][p][d] = mean_k inputs         (HBM-bound, 128 MiB)
//   2) pair_partial_kernel : GEMM-style 64x64 tile x 128-D-chunk partial d^2  (VALU/LDS-bound)
//   3) rowmin_kernel       : sum partials -> sqrt -> mask diag -> row min = anmin
//   4) diag_kernel         : cross-modality diagonal distances
//   5) loss_kernel         : weighted relu-mean -> scalar
#define P_IDS 128
#define D_DIM 4096
#define MARGIN_F 0.2f
#define NCHUNK 32            // partial-sum chunks (each 128 wide = 2 LDS passes of 64)

// ---------------- 1) centers: D-split for occupancy ----------------
__global__ __launch_bounds__(128) void centers_kernel(const float* __restrict__ in,
                                                      float* __restrict__ c, int K) {
    const int b  = blockIdx.x;            // m*P + p   (512)
    const int ds = blockIdx.y;            // 0..7  (512-float column slab)
    const float* src = in + (size_t)b * K * D_DIM + ds * 512;
    float* dst = c + (size_t)b * D_DIM + ds * 512;
    const float inv = 1.0f / (float)K;
    float4 acc = make_float4(0.f, 0.f, 0.f, 0.f);
    const int t = threadIdx.x;            // 0..127 -> one float4 column
    for (int k = 0; k < K; ++k) {
        float4 v = reinterpret_cast<const float4*>(src + (size_t)k * D_DIM)[t];
        acc.x += v.x; acc.y += v.y; acc.z += v.z; acc.w += v.w;
    }
    acc.x *= inv; acc.y *= inv; acc.z *= inv; acc.w *= inv;
    reinterpret_cast<float4*>(dst)[t] = acc;
}

// ---------------- 2) pairwise partial d^2, register-tiled ----------------
// Block: 256 threads (tx=tid&15, ty=tid>>4). Tile 64x64 pairs, per-thread 4x4.
// i rows: it*64 + ty*4 + r (consecutive); j rows: jt*64 + s*16 + tx (interleaved).
// LDS rows padded to 68 floats (272B = 17*16B: float4-aligned, bank-conflict-free <=2-way).
__global__ __launch_bounds__(256) void pair_partial_kernel(const float* __restrict__ c,
                                                           float* __restrict__ part) {
    __shared__ float As[64][68];
    __shared__ float Bs[64][68];
    const int tid = threadIdx.x;
    const int tx = tid & 15, ty = tid >> 4;
    const int bx = blockIdx.x;            // ((m*2)+it)*2 + jt  (16)
    const int m = bx >> 2, it = (bx >> 1) & 1, jt = bx & 1;
    const int dc = blockIdx.y;            // 0..31, covers D cols [dc*128, dc*128+128)
    const float* cm = c + (size_t)m * P_IDS * D_DIM;
    const float* gA = cm + (size_t)(it * 64) * D_DIM;
    const float* gB = cm + (size_t)(jt * 64) * D_DIM;

    float acc[4][4];
    #pragma unroll
    for (int r = 0; r < 4; ++r)
        #pragma unroll
        for (int s = 0; s < 4; ++s) acc[r][s] = 0.f;

    for (int ch = 0; ch < 2; ++ch) {      // two 64-float sub-chunks
        const int dbase = dc * 128 + ch * 64;
        __syncthreads();
        #pragma unroll
        for (int idx = 0; idx < 4; ++idx) {   // 1024 float4 per tile / 256 thr
            int li = idx * 256 + tid;
            int row = li >> 4, c4 = li & 15;
            float4 va = *reinterpret_cast<const float4*>(gA + (size_t)row * D_DIM + dbase + c4 * 4);
            float4 vb = *reinterpret_cast<const float4*>(gB + (size_t)row * D_DIM + dbase + c4 * 4);
            *reinterpret_cast<float4*>(&As[row][c4 * 4]) = va;
            *reinterpret_cast<float4*>(&Bs[row][c4 * 4]) = vb;
        }
        __syncthreads();
        #pragma unroll
        for (int d4 = 0; d4 < 16; ++d4) {
            float4 a[4], b[4];
            #pragma unroll
            for (int r = 0; r < 4; ++r)
                a[r] = *reinterpret_cast<const float4*>(&As[ty * 4 + r][d4 * 4]);
            #pragma unroll
            for (int s = 0; s < 4; ++s)
                b[s] = *reinterpret_cast<const float4*>(&Bs[s * 16 + tx][d4 * 4]);
            #pragma unroll
            for (int r = 0; r < 4; ++r)
                #pragma unroll
                for (int s = 0; s < 4; ++s) {
                    float dx = a[r].x - b[s].x, dy = a[r].y - b[s].y;
                    float dz = a[r].z - b[s].z, dw = a[r].w - b[s].w;
                    acc[r][s] = fmaf(dx, dx, acc[r][s]);
                    acc[r][s] = fmaf(dy, dy, acc[r][s]);
                    acc[r][s] = fmaf(dz, dz, acc[r][s]);
                    acc[r][s] = fmaf(dw, dw, acc[r][s]);
                }
        }
    }
    // part[dc][m][i][j]
    float* pbase = part + ((size_t)dc * 4 + m) * P_IDS * P_IDS;
    #pragma unroll
    for (int r = 0; r < 4; ++r) {
        int i = it * 64 + ty * 4 + r;
        #pragma unroll
        for (int s = 0; s < 4; ++s) {
            int j = jt * 64 + s * 16 + tx;
            pbase[i * P_IDS + j] = acc[r][s];
        }
    }
}

// ---------------- 3) reduce partials -> anmin ----------------
// Block = 256 thr = 2 (m,i) rows x 128 j. Sum NCHUNK partials, sqrt, mask diag, min.
__global__ __launch_bounds__(256) void rowmin_kernel(const float* __restrict__ part,
                                                     float* __restrict__ anmin) {
    const int tid = threadIdx.x;
    const int rowid = blockIdx.x * 2 + (tid >> 7);     // m*P + i
    const int j = tid & 127;
    const size_t base = (size_t)rowid * P_IDS + j;
    float sum = 0.f;
    #pragma unroll 4
    for (int dc = 0; dc < NCHUNK; ++dc)
        sum += part[(size_t)dc * 4 * P_IDS * P_IDS + base];
    float d = sqrtf(fmaxf(sum, 1e-12f));
    if (j == (rowid & (P_IDS - 1))) d = INFINITY;
    #pragma unroll
    for (int off = 32; off > 0; off >>= 1) d = fminf(d, __shfl_down(d, off, 64));
    __shared__ float wmin[4];
    if ((tid & 63) == 0) wmin[tid >> 6] = d;
    __syncthreads();
    if (tid == 0) {
        anmin[blockIdx.x * 2]     = fminf(wmin[0], wmin[1]);
        anmin[blockIdx.x * 2 + 1] = fminf(wmin[2], wmin[3]);
    }
}

// ---------------- 4) cross-modality diagonal distances ----------------
__global__ __launch_bounds__(256) void diag_kernel(const float* __restrict__ c,
                                                   float* __restrict__ diag) {
    const int i = blockIdx.x;
    const size_t PD = (size_t)P_IDS * D_DIM;
    const float4* r1 = reinterpret_cast<const float4*>(c + 0 * PD + (size_t)i * D_DIM);
    const float4* r2 = reinterpret_cast<const float4*>(c + 1 * PD + (size_t)i * D_DIM);
    const float4* r3 = reinterpret_cast<const float4*>(c + 2 * PD + (size_t)i * D_DIM);
    const float4* r4 = reinterpret_cast<const float4*>(c + 3 * PD + (size_t)i * D_DIM);
    float a23 = 0.f, a13 = 0.f, a14 = 0.f, a24 = 0.f;
    for (int t = threadIdx.x; t < (D_DIM >> 2); t += 256) {
        float4 v1 = r1[t], v2 = r2[t], v3 = r3[t], v4 = r4[t];
        float dx, dy, dz, dw;
        dx = v2.x - v3.x; dy = v2.y - v3.y; dz = v2.z - v3.z; dw = v2.w - v3.w;
        a23 = fmaf(dx, dx, a23); a23 = fmaf(dy, dy, a23);
        a23 = fmaf(dz, dz, a23); a23 = fmaf(dw, dw, a23);
        dx = v1.x - v3.x; dy = v1.y - v3.y; dz = v1.z - v3.z; dw = v1.w - v3.w;
        a13 = fmaf(dx, dx, a13); a13 = fmaf(dy, dy, a13);
        a13 = fmaf(dz, dz, a13); a13 = fmaf(dw, dw, a13);
        dx = v1.x - v4.x; dy = v1.y - v4.y; dz = v1.z - v4.z; dw = v1.w - v4.w;
        a14 = fmaf(dx, dx, a14); a14 = fmaf(dy, dy, a14);
        a14 = fmaf(dz, dz, a14); a14 = fmaf(dw, dw, a14);
        dx = v2.x - v4.x; dy = v2.y - v4.y; dz = v2.z - v4.z; dw = v2.w - v4.w;
        a24 = fmaf(dx, dx, a24); a24 = fmaf(dy, dy, a24);
        a24 = fmaf(dz, dz, a24); a24 = fmaf(dw, dw, a24);
    }
    const int wave = threadIdx.x >> 6, lane = threadIdx.x & 63;
    #pragma unroll
    for (int off = 32; off > 0; off >>= 1) {
        a23 += __shfl_down(a23, off, 64);
        a13 += __shfl_down(a13, off, 64);
        a14 += __shfl_down(a14, off, 64);
        a24 += __shfl_down(a24, off, 64);
    }
    __shared__ float red[4][4];
    if (lane == 0) { red[wave][0] = a23; red[wave][1] = a13; red[wave][2] = a14; red[wave][3] = a24; }
    __syncthreads();
    if (threadIdx.x == 0) {
        float s23 = red[0][0] + red[1][0] + red[2][0] + red[3][0];
        float s13 = red[0][1] + red[1][1] + red[2][1] + red[3][1];
        float s14 = red[0][2] + red[1][2] + red[2][2] + red[3][2];
        float s24 = red[0][3] + red[1][3] + red[2][3] + red[3][3];
        diag[0 * P_IDS + i] = sqrtf(fmaxf(s23, 1e-12f));  // ap123 = ||c2-c3||
        diag[1 * P_IDS + i] = sqrtf(fmaxf(s13, 1e-12f));  // an123 = ||c1-c3||
        diag[2 * P_IDS + i] = sqrtf(fmaxf(s14, 1e-12f));  // ap124 = ||c1-c4||
        diag[3 * P_IDS + i] = sqrtf(fmaxf(s24, 1e-12f));  // an124 = ||c2-c4||
    }
}

// ---------------- 5) final loss ----------------
__global__ __launch_bounds__(128) void loss_kernel(const float* __restrict__ anmin,
                                                   const float* __restrict__ diag,
                                                   float* __restrict__ out) {
    const int i = threadIdx.x;
    float ap123 = diag[0 * P_IDS + i], an123 = diag[1 * P_IDS + i];
    float ap124 = diag[2 * P_IDS + i], an124 = diag[3 * P_IDS + i];
    float an11 = anmin[0 * P_IDS + i], an22 = anmin[1 * P_IDS + i];
    float an33 = anmin[2 * P_IDS + i], an44 = anmin[3 * P_IDS + i];
    float s = fmaxf(ap123 - an123 + MARGIN_F, 0.f)
            + 0.5f * (fmaxf(ap123 - an33 + MARGIN_F, 0.f) +
                      fmaxf(ap123 - an11 + MARGIN_F, 0.f))
            + fmaxf(ap124 - an124 + MARGIN_F, 0.f)
            + 0.5f * (fmaxf(ap124 - an44 + MARGIN_F, 0.f) +
                      fmaxf(ap124 - an22 + MARGIN_F, 0.f));
    #pragma unroll
    for (int off = 32; off > 0; off >>= 1) s += __shfl_down(s, off, 64);
    __shared__ float w[2];
    if ((threadIdx.x & 63) == 0) w[threadIdx.x >> 6] = s;
    __syncthreads();
    if (threadIdx.x == 0) out[0] = (w[0] + w[1]) / (2.0f * (float)P_IDS);
}

extern "C" void kernel_launch(void* const* d_in, const int* in_sizes, int n_in,
                              void* d_out, int out_size, void* d_ws, size_t ws_size,
                              hipStream_t stream) {
    const float* in = (const float*)d_in[0];
    const int N = in_sizes[1];            // 8192
    const int K = N / (4 * P_IDS);        // 16

    float* c     = (float*)d_ws;                              // 4*128*4096 f32 = 8 MiB
    float* part  = c + (size_t)4 * P_IDS * D_DIM;             // 32*4*128*128 f32 = 8.4 MB
    float* anmin = part + (size_t)NCHUNK * 4 * P_IDS * P_IDS; // 512 f32
    float* diag  = anmin + 4 * P_IDS;                         // 512 f32

    hipLaunchKernelGGL(centers_kernel, dim3(4 * P_IDS, 8), dim3(128), 0, stream, in, c, K);
    hipLaunchKernelGGL(pair_partial_kernel, dim3(16, NCHUNK), dim3(256), 0, stream, c, part);
    hipLaunchKernelGGL(rowmin_kernel, dim3(2 * P_IDS), dim3(256), 0, stream, part, anmin);
    hipLaunchKernelGGL(diag_kernel, dim3(P_IDS), dim3(256), 0, stream, c, diag);
    hipLaunchKernelGGL(loss_kernel, dim3(1), dim3(128), 0, stream, anmin, diag, (float*)d_out);
}